// Round 8
// baseline (609.124 us; speedup 1.0000x reference)
//
#include <hip/hip_runtime.h>
#include <hip/hip_fp16.h>

#define N_NODES  100000
#define N_EDGES  1200000
#define N_GRAPHS 1024
#define F        64
#define BN_EPS   1e-5f
#define NBUCK    ((N_NODES + 255) / 256)       // 391 buckets of 256 node IDs
#define MT       64                             // GEMM nodes per block
#define GEMM_BLOCKS ((N_NODES + MT - 1) / MT)   // 1563
#define SCAT_BLOCKS 1024
#define CE       3584                           // per-bucket slab capacity
                                                // (binomial mu=3072 sd=55; +9.2sd;
                                                //  measured max ~3250; clamped)

typedef _Float16 f16x8 __attribute__((ext_vector_type(8)));
typedef float f32x4 __attribute__((ext_vector_type(4)));

// ---------------------------------------------------------------------------
// prepw: one-time W^T -> fp16.  Wh[c][k], c<64 = Wself col c, c>=64 = Wneigh.
// ---------------------------------------------------------------------------
__global__ __launch_bounds__(256) void prepw(
    const float* __restrict__ Wself, const float* __restrict__ Wneigh,
    __half* __restrict__ Wh) {
  int t = threadIdx.x;
  for (int i = t; i < 128 * 64; i += 256) {
    int c = i >> 6, k = i & 63;
    float v = (c < 64) ? Wself[k * 64 + c] : Wneigh[k * 64 + (c - 64)];
    Wh[i] = __float2half_rn(v);
  }
}

// ---------------------------------------------------------------------------
// gemm: 64 nodes x 128 outs x K=64 per block via mfma_f32_16x16x32_f16,
// no LDS/barriers (R6-proven path, now a standalone kernel for attribution).
// Swapped operands -> D^T: lane holds (node=lane&15, f=(lane>>4)*4+reg).
// ---------------------------------------------------------------------------
__global__ __launch_bounds__(256) void gemm(
    const float* __restrict__ feats, const __half* __restrict__ Wh,
    __half* __restrict__ Uh, __half* __restrict__ Zh) {
  int t = threadIdx.x;
  int mbase = blockIdx.x * MT;
  int wave = t >> 6, lane = t & 63;
  int lr = lane & 15, kg = lane >> 4;

  int n0 = mbase + wave * 16 + lr;
  int n0c = (n0 < N_NODES) ? n0 : (N_NODES - 1);
  const float* fp = feats + (size_t)n0c * F + kg * 8;

  f16x8 a[2];
#pragma unroll
  for (int h = 0; h < 2; h++) {
    float4 x0 = *(const float4*)(fp + h * 32);
    float4 x1 = *(const float4*)(fp + h * 32 + 4);
    a[h] = (f16x8){(_Float16)x0.x, (_Float16)x0.y, (_Float16)x0.z, (_Float16)x0.w,
                   (_Float16)x1.x, (_Float16)x1.y, (_Float16)x1.z, (_Float16)x1.w};
  }

  f32x4 acc[8];
#pragma unroll
  for (int j = 0; j < 8; j++) acc[j] = (f32x4){0.f, 0.f, 0.f, 0.f};

  const __half* wp = Wh + (size_t)lr * 64 + kg * 8;   // row (j*16+lr), k-offset
#pragma unroll
  for (int h = 0; h < 2; h++) {
#pragma unroll
    for (int j = 0; j < 8; j++) {
      f16x8 wv = *(const f16x8*)(wp + j * 16 * 64 + h * 32);
      acc[j] = __builtin_amdgcn_mfma_f32_16x16x32_f16(wv, a[h], acc[j], 0, 0, 0);
    }
  }

  if (n0 < N_NODES) {
#pragma unroll
    for (int j = 0; j < 8; j++) {
      int f = j * 16 + kg * 4;
      union { __half h[4]; uint2 u; } pk;
      pk.h[0] = __float2half_rn(acc[j][0]);
      pk.h[1] = __float2half_rn(acc[j][1]);
      pk.h[2] = __float2half_rn(acc[j][2]);
      pk.h[3] = __float2half_rn(acc[j][3]);
      __half* outp = (f < 64) ? (Uh + (size_t)n0 * F + f)
                              : (Zh + (size_t)n0 * F + (f - 64));
      *(uint2*)outp = pk.u;
    }
  }
}

// ---------------------------------------------------------------------------
// scat: single-pass, zero LDS, zero barriers. Per edge: reserve one slot in
// the dst bucket via global atomicAdd(gcur[391]) and write the packed pair
// to the bucket slab. dst/src read ONCE (int4). Write frontier = 391 cursors
// advancing sequentially -> line locality (the property R7's CSR lacked).
// gcur[b] ends as the bucket count, same semantics gather_place expects.
// ---------------------------------------------------------------------------
__global__ __launch_bounds__(256) void scat(
    const int* __restrict__ src, const int* __restrict__ dst,
    int* __restrict__ gcur, int* __restrict__ pairs) {
  int tid = blockIdx.x * 256 + threadIdx.x;
  int nth = gridDim.x * 256;
  for (int q = tid; q < N_EDGES / 4; q += nth) {   // 1.2M % 4 == 0
    int e = q * 4;
    int4 dv = *(const int4*)(dst + e);
    int4 sv = *(const int4*)(src + e);
    int p0 = atomicAdd(&gcur[dv.x >> 8], 1);
    int p1 = atomicAdd(&gcur[dv.y >> 8], 1);
    int p2 = atomicAdd(&gcur[dv.z >> 8], 1);
    int p3 = atomicAdd(&gcur[dv.w >> 8], 1);
    if (p0 < CE) pairs[(size_t)(dv.x >> 8) * CE + p0] =
        (int)((((unsigned)dv.x & 255u) << 24) | (unsigned)sv.x);
    if (p1 < CE) pairs[(size_t)(dv.y >> 8) * CE + p1] =
        (int)((((unsigned)dv.y & 255u) << 24) | (unsigned)sv.y);
    if (p2 < CE) pairs[(size_t)(dv.z >> 8) * CE + p2] =
        (int)((((unsigned)dv.z & 255u) << 24) | (unsigned)sv.z);
    if (p3 < CE) pairs[(size_t)(dv.w >> 8) * CE + p3] =
        (int)((((unsigned)dv.w & 255u) << 24) | (unsigned)sv.w);
  }
}

// ---------------------------------------------------------------------------
// gather_place: fused [place | gather]. One 1024-thread block per bucket.
// Reads its slab pairs[b*CE .. b*CE+E), E = gcur[b].  (R6-proven, verbatim.)
// ---------------------------------------------------------------------------
__global__ __launch_bounds__(1024) void gather_place(
    const __half* __restrict__ Uh, const __half* __restrict__ Zh,
    const int* __restrict__ pairs, const int* __restrict__ gcur,
    const float* __restrict__ bneigh, const int* __restrict__ gids,
    int* __restrict__ hgbits) {
  __shared__ int eidx_l[CE];     // 14.3 KB
  __shared__ int rsl[256];
  __shared__ int lh[256];
  __shared__ int cur[256];
  int b = blockIdx.x, t = threadIdx.x;
  int nb0 = b << 8;
  const int* pr = pairs + (size_t)b * CE;
  int E = gcur[b]; if (E > CE) E = CE;   // capacity clamp (never hit: max~3250)

  // --- phase 1: local place ---
  if (t < 256) lh[t] = 0;
  __syncthreads();
  for (int e = t; e < E; e += 1024)
    atomicAdd(&lh[((unsigned)pr[e]) >> 24], 1);
  __syncthreads();
  if (t < 256) cur[t] = lh[t];
  __syncthreads();
  for (int off = 1; off < 256; off <<= 1) {
    int u = (t < 256 && t >= off) ? cur[t - off] : 0;
    __syncthreads();
    if (t < 256) cur[t] += u;
    __syncthreads();
  }
  if (t < 256) { int ex = cur[t] - lh[t]; rsl[t] = ex; cur[t] = ex; }
  __syncthreads();
  for (int e = t; e < E; e += 1024) {
    unsigned p = (unsigned)pr[e];
    int pos = atomicAdd(&cur[p >> 24], 1);
    eidx_l[pos] = (int)(p & 0xFFFFFFu);
  }
  __syncthreads();

  // --- phase 2: gather + SAGE update + ReLU + per-graph max ---
  int wave = t >> 6, lane = t & 63;
  int fl = lane & 15, sub = lane >> 4;
  float4 b4 = *(const float4*)(bneigh + 4 * fl);
  int nl = wave * 16;
  int nend = nl + 16;
  if (nb0 + nl >= N_NODES) return;
  if (nb0 + nend > N_NODES) nend = N_NODES - nb0;

  int curg = gids[nb0 + nl];
  float4 gmax = {0.f, 0.f, 0.f, 0.f};

  for (; nl < nend; nl++) {
    int node = nb0 + nl;
    int rr  = rsl[nl];
    int deg = lh[nl];
    uint2 ur = *(const uint2*)(Uh + (size_t)node * F + 4 * fl);
    float sx = 0.f, sy = 0.f, sz = 0.f, sw = 0.f;
    for (int jj = 0; jj < deg; jj += 16) {
      int j0 = jj + sub;
      int s0 = (j0      < deg) ? eidx_l[rr + j0]      : 0;  // LDS broadcast
      int s1 = (j0 + 4  < deg) ? eidx_l[rr + j0 + 4]  : 0;
      int s2 = (j0 + 8  < deg) ? eidx_l[rr + j0 + 8]  : 0;
      int s3 = (j0 + 12 < deg) ? eidx_l[rr + j0 + 12] : 0;
      uint2 z0 = *(const uint2*)(Zh + (size_t)s0 * F + 4 * fl);
      uint2 z1 = *(const uint2*)(Zh + (size_t)s1 * F + 4 * fl);
      uint2 z2 = *(const uint2*)(Zh + (size_t)s2 * F + 4 * fl);
      uint2 z3 = *(const uint2*)(Zh + (size_t)s3 * F + 4 * fl);
      if (j0 < deg) {
        float2 f0 = __half22float2(*(__half2*)&z0.x);
        float2 f1 = __half22float2(*(__half2*)&z0.y);
        sx += f0.x; sy += f0.y; sz += f1.x; sw += f1.y;
      }
      if (j0 + 4 < deg) {
        float2 f0 = __half22float2(*(__half2*)&z1.x);
        float2 f1 = __half22float2(*(__half2*)&z1.y);
        sx += f0.x; sy += f0.y; sz += f1.x; sw += f1.y;
      }
      if (j0 + 8 < deg) {
        float2 f0 = __half22float2(*(__half2*)&z2.x);
        float2 f1 = __half22float2(*(__half2*)&z2.y);
        sx += f0.x; sy += f0.y; sz += f1.x; sw += f1.y;
      }
      if (j0 + 12 < deg) {
        float2 f0 = __half22float2(*(__half2*)&z3.x);
        float2 f1 = __half22float2(*(__half2*)&z3.y);
        sx += f0.x; sy += f0.y; sz += f1.x; sw += f1.y;
      }
    }
    sx += __shfl_xor(sx, 16); sy += __shfl_xor(sy, 16);
    sz += __shfl_xor(sz, 16); sw += __shfl_xor(sw, 16);
    sx += __shfl_xor(sx, 32); sy += __shfl_xor(sy, 32);
    sz += __shfl_xor(sz, 32); sw += __shfl_xor(sw, 32);
    float inv = 1.0f / fmaxf((float)deg, 1.0f);

    int g = gids[node];
    if (g != curg) {
      if (sub == 0) {
        int* hp = hgbits + (size_t)curg * F + 4 * fl;
        atomicMax(hp + 0, __float_as_int(gmax.x));
        atomicMax(hp + 1, __float_as_int(gmax.y));
        atomicMax(hp + 2, __float_as_int(gmax.z));
        atomicMax(hp + 3, __float_as_int(gmax.w));
      }
      curg = g; gmax = make_float4(0.f, 0.f, 0.f, 0.f);
    }

    float2 uf0 = __half22float2(*(__half2*)&ur.x);
    float2 uf1 = __half22float2(*(__half2*)&ur.y);
    gmax.x = fmaxf(gmax.x, fmaxf(uf0.x + sx * inv + b4.x, 0.f));
    gmax.y = fmaxf(gmax.y, fmaxf(uf0.y + sy * inv + b4.y, 0.f));
    gmax.z = fmaxf(gmax.z, fmaxf(uf1.x + sz * inv + b4.z, 0.f));
    gmax.w = fmaxf(gmax.w, fmaxf(uf1.y + sw * inv + b4.w, 0.f));
  }
  if (sub == 0) {
    int* hp = hgbits + (size_t)curg * F + 4 * fl;
    atomicMax(hp + 0, __float_as_int(gmax.x));
    atomicMax(hp + 1, __float_as_int(gmax.y));
    atomicMax(hp + 2, __float_as_int(gmax.z));
    atomicMax(hp + 3, __float_as_int(gmax.w));
  }
}

// ---------------------------------------------------------------------------
// MLP head: weights staged in LDS once, 2 graphs per block.
// ---------------------------------------------------------------------------
#define GPB 2
__global__ __launch_bounds__(128) void mlp(
    const float* __restrict__ hg,
    const float* __restrict__ W1, const float* __restrict__ b1,
    const float* __restrict__ g1, const float* __restrict__ be1,
    const float* __restrict__ rm1, const float* __restrict__ rv1,
    const float* __restrict__ W2, const float* __restrict__ b2,
    const float* __restrict__ g2, const float* __restrict__ be2,
    const float* __restrict__ rm2, const float* __restrict__ rv2,
    const float* __restrict__ W3, const float* __restrict__ b3,
    float* __restrict__ out) {
  __shared__ float W1s[64 * 128];
  __shared__ float W2s[128 * 64];
  __shared__ float W3s[64];
  __shared__ float sc1[128], sh1[128], b1s[128];
  __shared__ float sc2[64],  sh2[64],  b2s[64];
  __shared__ float s0[64], s1[128], s2[64];
  int t = threadIdx.x;

  for (int i = t; i < 64 * 128; i += 128) W1s[i] = W1[i];
  for (int i = t; i < 128 * 64; i += 128) W2s[i] = W2[i];
  if (t < 64) W3s[t] = W3[t];
  {
    float iv = rsqrtf(rv1[t] + BN_EPS);
    float sc = g1[t] * iv;
    sc1[t] = sc; sh1[t] = be1[t] - rm1[t] * sc; b1s[t] = b1[t];
  }
  if (t < 64) {
    float iv = rsqrtf(rv2[t] + BN_EPS);
    float sc = g2[t] * iv;
    sc2[t] = sc; sh2[t] = be2[t] - rm2[t] * sc; b2s[t] = b2[t];
  }
  __syncthreads();

  for (int gg = 0; gg < GPB; gg++) {
    int g = blockIdx.x * GPB + gg;
    if (t < 64) s0[t] = hg[(size_t)g * F + t];
    __syncthreads();
    {
      float acc = b1s[t];
      for (int i = 0; i < 64; i++) acc += s0[i] * W1s[i * 128 + t];
      acc = fmaxf(acc, 0.0f);
      s1[t] = acc * sc1[t] + sh1[t];
    }
    __syncthreads();
    if (t < 64) {
      float acc = b2s[t];
      for (int i = 0; i < 128; i++) acc += s1[i] * W2s[i * 64 + t];
      acc = fmaxf(acc, 0.0f);
      s2[t] = acc * sc2[t] + sh2[t];
    }
    __syncthreads();
    if (t < 64) {
      float p = s2[t] * W3s[t];
      for (int off = 32; off > 0; off >>= 1) p += __shfl_down(p, off);
      if (t == 0) out[g] = p + b3[0];
    }
    __syncthreads();
  }
}

// ---------------------------------------------------------------------------
extern "C" void kernel_launch(void* const* d_in, const int* in_sizes, int n_in,
                              void* d_out, int out_size, void* d_ws, size_t ws_size,
                              hipStream_t stream) {
  const float* feats  = (const float*)d_in[0];
  const int*   src    = (const int*)d_in[1];
  const int*   dst    = (const int*)d_in[2];
  const int*   gids   = (const int*)d_in[3];
  const float* Wself  = (const float*)d_in[4];
  const float* Wneigh = (const float*)d_in[5];
  const float* bneigh = (const float*)d_in[6];
  const float* W1  = (const float*)d_in[7];
  const float* b1  = (const float*)d_in[8];
  const float* g1  = (const float*)d_in[9];
  const float* be1 = (const float*)d_in[10];
  const float* rm1 = (const float*)d_in[11];
  const float* rv1 = (const float*)d_in[12];
  const float* W2  = (const float*)d_in[13];
  const float* b2  = (const float*)d_in[14];
  const float* g2  = (const float*)d_in[15];
  const float* be2 = (const float*)d_in[16];
  const float* rm2 = (const float*)d_in[17];
  const float* rv2 = (const float*)d_in[18];
  const float* W3  = (const float*)d_in[19];
  const float* b3  = (const float*)d_in[20];

  // ws layout: Uh | Zh | Wh | gcur | hgbits | pairs  (gcur+hgbits = one memset)
  __half* Uh   = (__half*)d_ws;                      // N_NODES*64 halves
  __half* Zh   = Uh + (size_t)N_NODES * F;           // N_NODES*64 halves
  __half* Wh   = Zh + (size_t)N_NODES * F;           // 128*64 halves
  int* gcur    = (int*)(Wh + 128 * 64);              // NBUCK
  int* hgbits  = gcur + NBUCK;                       // N_GRAPHS*F
  int* pairs   = hgbits + (size_t)N_GRAPHS * F;      // NBUCK*CE slabs

  hipMemsetAsync(gcur, 0, (NBUCK + N_GRAPHS * F) * sizeof(int), stream);

  prepw<<<1, 256, 0, stream>>>(Wself, Wneigh, Wh);
  gemm<<<GEMM_BLOCKS, 256, 0, stream>>>(feats, Wh, Uh, Zh);
  scat<<<SCAT_BLOCKS, 256, 0, stream>>>(src, dst, gcur, pairs);
  gather_place<<<NBUCK, 1024, 0, stream>>>(Uh, Zh, pairs, gcur, bneigh,
                                           gids, hgbits);
  mlp<<<N_GRAPHS / GPB, 128, 0, stream>>>((const float*)hgbits,
                                          W1, b1, g1, be1, rm1, rv1,
                                          W2, b2, g2, be2, rm2, rv2, W3, b3,
                                          (float*)d_out);
}

// Round 9
// 193.758 us; speedup vs baseline: 3.1437x; 3.1437x over previous
//
#include <hip/hip_runtime.h>
#include <hip/hip_fp16.h>

#define N_NODES  100000
#define N_EDGES  1200000
#define N_GRAPHS 1024
#define F        64
#define BN_EPS   1e-5f
#define NBUCK    ((N_NODES + 255) / 256)       // 391 buckets of 256 node IDs
#define NBLK     128                            // scatter chunks (chain depth
                                                //  per gcur address = NBLK;
                                                //  512 -> ~51us serial @~100ns/op)
#define CHUNK    9376                           // NBLK*CHUNK >= N_EDGES; %4==0
#define MT       64                             // GEMM nodes per block
#define GEMM_BLOCKS ((N_NODES + MT - 1) / MT)   // 1563
#define CE       3584                           // per-bucket slab capacity
                                                // (binomial mu=3072 sd=55; +9.2sd;
                                                //  measured max ~3250; clamped)

typedef _Float16 f16x8 __attribute__((ext_vector_type(8)));
typedef float f32x4 __attribute__((ext_vector_type(4)));

// ---------------------------------------------------------------------------
// prepw: one-time W^T -> fp16.  Wh[c][k], c<64 = Wself col c, c>=64 = Wneigh.
// ---------------------------------------------------------------------------
__global__ __launch_bounds__(256) void prepw(
    const float* __restrict__ Wself, const float* __restrict__ Wneigh,
    __half* __restrict__ Wh) {
  int t = threadIdx.x;
  for (int i = t; i < 128 * 64; i += 256) {
    int c = i >> 6, k = i & 63;
    float v = (c < 64) ? Wself[k * 64 + c] : Wneigh[k * 64 + (c - 64)];
    Wh[i] = __float2half_rn(v);
  }
}

// ---------------------------------------------------------------------------
// prepscat: fused [scat | gemm_uz].
// blocks [0,NBLK): scat — int4 LDS hist of its 9376-edge chunk, ONE
//   reservation atomic per (block,bucket) into gcur[391] (chain depth 128),
//   LDS-cursor scatter into per-bucket slab pairs[b*CE ...].
// blocks [NBLK,+GEMM_BLOCKS): GEMM 64 nodes x 128 outs x K=64 via
//   mfma_f32_16x16x32_f16, no LDS/barriers (R6-proven).
//   Swapped operands -> D^T: lane holds (node=lane&15, f=(lane>>4)*4+reg).
// ---------------------------------------------------------------------------
__global__ __launch_bounds__(256) void prepscat(
    const float* __restrict__ feats, const __half* __restrict__ Wh,
    __half* __restrict__ Uh, __half* __restrict__ Zh,
    const int* __restrict__ src, const int* __restrict__ dst,
    int* __restrict__ gcur, int* __restrict__ pairs) {
  __shared__ int lh[NBUCK];
  __shared__ int lcur[NBUCK];
  int t = threadIdx.x;

  if (blockIdx.x < NBLK) {
    // ---- scat path ----
    int b = blockIdx.x;
    for (int i = t; i < NBUCK; i += 256) lh[i] = 0;
    __syncthreads();
    int e0 = b * CHUNK;
    int e1 = e0 + CHUNK; if (e1 > N_EDGES) e1 = N_EDGES;
    for (int q = t; q < CHUNK / 4; q += 256) {
      int e = e0 + q * 4;
      if (e + 4 <= e1) {
        int4 dv = *(const int4*)(dst + e);
        atomicAdd(&lh[dv.x >> 8], 1);
        atomicAdd(&lh[dv.y >> 8], 1);
        atomicAdd(&lh[dv.z >> 8], 1);
        atomicAdd(&lh[dv.w >> 8], 1);
      } else {
        for (int k = 0; k < 4; k++)
          if (e + k < e1) atomicAdd(&lh[dst[e + k] >> 8], 1);
      }
    }
    __syncthreads();
    for (int i = t; i < NBUCK; i += 256) {
      int c = lh[i];
      lcur[i] = c ? atomicAdd(&gcur[i], c) : 0;   // reserve [base, base+c)
    }
    __syncthreads();
    for (int q = t; q < CHUNK / 4; q += 256) {
      int e = e0 + q * 4;
      if (e + 4 <= e1) {
        int4 dv = *(const int4*)(dst + e);
        int4 sv = *(const int4*)(src + e);
        int p0 = atomicAdd(&lcur[dv.x >> 8], 1);
        int p1 = atomicAdd(&lcur[dv.y >> 8], 1);
        int p2 = atomicAdd(&lcur[dv.z >> 8], 1);
        int p3 = atomicAdd(&lcur[dv.w >> 8], 1);
        if (p0 < CE) pairs[(size_t)(dv.x >> 8) * CE + p0] =
            (int)((((unsigned)dv.x & 255u) << 24) | (unsigned)sv.x);
        if (p1 < CE) pairs[(size_t)(dv.y >> 8) * CE + p1] =
            (int)((((unsigned)dv.y & 255u) << 24) | (unsigned)sv.y);
        if (p2 < CE) pairs[(size_t)(dv.z >> 8) * CE + p2] =
            (int)((((unsigned)dv.z & 255u) << 24) | (unsigned)sv.z);
        if (p3 < CE) pairs[(size_t)(dv.w >> 8) * CE + p3] =
            (int)((((unsigned)dv.w & 255u) << 24) | (unsigned)sv.w);
      } else {
        for (int k = 0; k < 4; k++)
          if (e + k < e1) {
            int d = dst[e + k];
            int pos = atomicAdd(&lcur[d >> 8], 1);
            if (pos < CE)
              pairs[(size_t)(d >> 8) * CE + pos] =
                  (int)((((unsigned)d & 255u) << 24) | (unsigned)src[e + k]);
          }
      }
    }
    return;
  }

  // ---- GEMM path (no LDS, no barriers; 16 nodes/wave) ----
  int mbase = (blockIdx.x - NBLK) * MT;
  int wave = t >> 6, lane = t & 63;
  int lr = lane & 15, kg = lane >> 4;

  int n0 = mbase + wave * 16 + lr;
  int n0c = (n0 < N_NODES) ? n0 : (N_NODES - 1);
  const float* fp = feats + (size_t)n0c * F + kg * 8;

  f16x8 a[2];
#pragma unroll
  for (int h = 0; h < 2; h++) {
    float4 x0 = *(const float4*)(fp + h * 32);
    float4 x1 = *(const float4*)(fp + h * 32 + 4);
    a[h] = (f16x8){(_Float16)x0.x, (_Float16)x0.y, (_Float16)x0.z, (_Float16)x0.w,
                   (_Float16)x1.x, (_Float16)x1.y, (_Float16)x1.z, (_Float16)x1.w};
  }

  f32x4 acc[8];
#pragma unroll
  for (int j = 0; j < 8; j++) acc[j] = (f32x4){0.f, 0.f, 0.f, 0.f};

  const __half* wp = Wh + (size_t)lr * 64 + kg * 8;   // row (j*16+lr), k-offset
#pragma unroll
  for (int h = 0; h < 2; h++) {
#pragma unroll
    for (int j = 0; j < 8; j++) {
      f16x8 wv = *(const f16x8*)(wp + j * 16 * 64 + h * 32);
      acc[j] = __builtin_amdgcn_mfma_f32_16x16x32_f16(wv, a[h], acc[j], 0, 0, 0);
    }
  }

  // --- epilogue: D^T layout -> lane packs 4 consecutive feats of one node ---
  if (n0 < N_NODES) {
#pragma unroll
    for (int j = 0; j < 8; j++) {
      int f = j * 16 + kg * 4;
      union { __half h[4]; uint2 u; } pk;
      pk.h[0] = __float2half_rn(acc[j][0]);
      pk.h[1] = __float2half_rn(acc[j][1]);
      pk.h[2] = __float2half_rn(acc[j][2]);
      pk.h[3] = __float2half_rn(acc[j][3]);
      __half* outp = (f < 64) ? (Uh + (size_t)n0 * F + f)
                              : (Zh + (size_t)n0 * F + (f - 64));
      *(uint2*)outp = pk.u;
    }
  }
}

// ---------------------------------------------------------------------------
// gather_place: fused [place | gather]. One 1024-thread block per bucket.
// Reads its slab pairs[b*CE .. b*CE+E), E = gcur[b].  (R6-proven, verbatim.)
// ---------------------------------------------------------------------------
__global__ __launch_bounds__(1024) void gather_place(
    const __half* __restrict__ Uh, const __half* __restrict__ Zh,
    const int* __restrict__ pairs, const int* __restrict__ gcur,
    const float* __restrict__ bneigh, const int* __restrict__ gids,
    int* __restrict__ hgbits) {
  __shared__ int eidx_l[CE];     // 14.3 KB
  __shared__ int rsl[256];
  __shared__ int lh[256];
  __shared__ int cur[256];
  int b = blockIdx.x, t = threadIdx.x;
  int nb0 = b << 8;
  const int* pr = pairs + (size_t)b * CE;
  int E = gcur[b]; if (E > CE) E = CE;   // capacity clamp (never hit: max~3250)

  // --- phase 1: local place ---
  if (t < 256) lh[t] = 0;
  __syncthreads();
  for (int e = t; e < E; e += 1024)
    atomicAdd(&lh[((unsigned)pr[e]) >> 24], 1);
  __syncthreads();
  if (t < 256) cur[t] = lh[t];
  __syncthreads();
  for (int off = 1; off < 256; off <<= 1) {
    int u = (t < 256 && t >= off) ? cur[t - off] : 0;
    __syncthreads();
    if (t < 256) cur[t] += u;
    __syncthreads();
  }
  if (t < 256) { int ex = cur[t] - lh[t]; rsl[t] = ex; cur[t] = ex; }
  __syncthreads();
  for (int e = t; e < E; e += 1024) {
    unsigned p = (unsigned)pr[e];
    int pos = atomicAdd(&cur[p >> 24], 1);
    eidx_l[pos] = (int)(p & 0xFFFFFFu);
  }
  __syncthreads();

  // --- phase 2: gather + SAGE update + ReLU + per-graph max ---
  int wave = t >> 6, lane = t & 63;
  int fl = lane & 15, sub = lane >> 4;
  float4 b4 = *(const float4*)(bneigh + 4 * fl);
  int nl = wave * 16;
  int nend = nl + 16;
  if (nb0 + nl >= N_NODES) return;
  if (nb0 + nend > N_NODES) nend = N_NODES - nb0;

  int curg = gids[nb0 + nl];
  float4 gmax = {0.f, 0.f, 0.f, 0.f};

  for (; nl < nend; nl++) {
    int node = nb0 + nl;
    int rr  = rsl[nl];
    int deg = lh[nl];
    uint2 ur = *(const uint2*)(Uh + (size_t)node * F + 4 * fl);
    float sx = 0.f, sy = 0.f, sz = 0.f, sw = 0.f;
    for (int jj = 0; jj < deg; jj += 16) {
      int j0 = jj + sub;
      int s0 = (j0      < deg) ? eidx_l[rr + j0]      : 0;  // LDS broadcast
      int s1 = (j0 + 4  < deg) ? eidx_l[rr + j0 + 4]  : 0;
      int s2 = (j0 + 8  < deg) ? eidx_l[rr + j0 + 8]  : 0;
      int s3 = (j0 + 12 < deg) ? eidx_l[rr + j0 + 12] : 0;
      uint2 z0 = *(const uint2*)(Zh + (size_t)s0 * F + 4 * fl);
      uint2 z1 = *(const uint2*)(Zh + (size_t)s1 * F + 4 * fl);
      uint2 z2 = *(const uint2*)(Zh + (size_t)s2 * F + 4 * fl);
      uint2 z3 = *(const uint2*)(Zh + (size_t)s3 * F + 4 * fl);
      if (j0 < deg) {
        float2 f0 = __half22float2(*(__half2*)&z0.x);
        float2 f1 = __half22float2(*(__half2*)&z0.y);
        sx += f0.x; sy += f0.y; sz += f1.x; sw += f1.y;
      }
      if (j0 + 4 < deg) {
        float2 f0 = __half22float2(*(__half2*)&z1.x);
        float2 f1 = __half22float2(*(__half2*)&z1.y);
        sx += f0.x; sy += f0.y; sz += f1.x; sw += f1.y;
      }
      if (j0 + 8 < deg) {
        float2 f0 = __half22float2(*(__half2*)&z2.x);
        float2 f1 = __half22float2(*(__half2*)&z2.y);
        sx += f0.x; sy += f0.y; sz += f1.x; sw += f1.y;
      }
      if (j0 + 12 < deg) {
        float2 f0 = __half22float2(*(__half2*)&z3.x);
        float2 f1 = __half22float2(*(__half2*)&z3.y);
        sx += f0.x; sy += f0.y; sz += f1.x; sw += f1.y;
      }
    }
    sx += __shfl_xor(sx, 16); sy += __shfl_xor(sy, 16);
    sz += __shfl_xor(sz, 16); sw += __shfl_xor(sw, 16);
    sx += __shfl_xor(sx, 32); sy += __shfl_xor(sy, 32);
    sz += __shfl_xor(sz, 32); sw += __shfl_xor(sw, 32);
    float inv = 1.0f / fmaxf((float)deg, 1.0f);

    int g = gids[node];
    if (g != curg) {
      if (sub == 0) {
        int* hp = hgbits + (size_t)curg * F + 4 * fl;
        atomicMax(hp + 0, __float_as_int(gmax.x));
        atomicMax(hp + 1, __float_as_int(gmax.y));
        atomicMax(hp + 2, __float_as_int(gmax.z));
        atomicMax(hp + 3, __float_as_int(gmax.w));
      }
      curg = g; gmax = make_float4(0.f, 0.f, 0.f, 0.f);
    }

    float2 uf0 = __half22float2(*(__half2*)&ur.x);
    float2 uf1 = __half22float2(*(__half2*)&ur.y);
    gmax.x = fmaxf(gmax.x, fmaxf(uf0.x + sx * inv + b4.x, 0.f));
    gmax.y = fmaxf(gmax.y, fmaxf(uf0.y + sy * inv + b4.y, 0.f));
    gmax.z = fmaxf(gmax.z, fmaxf(uf1.x + sz * inv + b4.z, 0.f));
    gmax.w = fmaxf(gmax.w, fmaxf(uf1.y + sw * inv + b4.w, 0.f));
  }
  if (sub == 0) {
    int* hp = hgbits + (size_t)curg * F + 4 * fl;
    atomicMax(hp + 0, __float_as_int(gmax.x));
    atomicMax(hp + 1, __float_as_int(gmax.y));
    atomicMax(hp + 2, __float_as_int(gmax.z));
    atomicMax(hp + 3, __float_as_int(gmax.w));
  }
}

// ---------------------------------------------------------------------------
// MLP head: weights staged in LDS once, 2 graphs per block.
// ---------------------------------------------------------------------------
#define GPB 2
__global__ __launch_bounds__(128) void mlp(
    const float* __restrict__ hg,
    const float* __restrict__ W1, const float* __restrict__ b1,
    const float* __restrict__ g1, const float* __restrict__ be1,
    const float* __restrict__ rm1, const float* __restrict__ rv1,
    const float* __restrict__ W2, const float* __restrict__ b2,
    const float* __restrict__ g2, const float* __restrict__ be2,
    const float* __restrict__ rm2, const float* __restrict__ rv2,
    const float* __restrict__ W3, const float* __restrict__ b3,
    float* __restrict__ out) {
  __shared__ float W1s[64 * 128];
  __shared__ float W2s[128 * 64];
  __shared__ float W3s[64];
  __shared__ float sc1[128], sh1[128], b1s[128];
  __shared__ float sc2[64],  sh2[64],  b2s[64];
  __shared__ float s0[64], s1[128], s2[64];
  int t = threadIdx.x;

  for (int i = t; i < 64 * 128; i += 128) W1s[i] = W1[i];
  for (int i = t; i < 128 * 64; i += 128) W2s[i] = W2[i];
  if (t < 64) W3s[t] = W3[t];
  {
    float iv = rsqrtf(rv1[t] + BN_EPS);
    float sc = g1[t] * iv;
    sc1[t] = sc; sh1[t] = be1[t] - rm1[t] * sc; b1s[t] = b1[t];
  }
  if (t < 64) {
    float iv = rsqrtf(rv2[t] + BN_EPS);
    float sc = g2[t] * iv;
    sc2[t] = sc; sh2[t] = be2[t] - rm2[t] * sc; b2s[t] = b2[t];
  }
  __syncthreads();

  for (int gg = 0; gg < GPB; gg++) {
    int g = blockIdx.x * GPB + gg;
    if (t < 64) s0[t] = hg[(size_t)g * F + t];
    __syncthreads();
    {
      float acc = b1s[t];
      for (int i = 0; i < 64; i++) acc += s0[i] * W1s[i * 128 + t];
      acc = fmaxf(acc, 0.0f);
      s1[t] = acc * sc1[t] + sh1[t];
    }
    __syncthreads();
    if (t < 64) {
      float acc = b2s[t];
      for (int i = 0; i < 128; i++) acc += s1[i] * W2s[i * 64 + t];
      acc = fmaxf(acc, 0.0f);
      s2[t] = acc * sc2[t] + sh2[t];
    }
    __syncthreads();
    if (t < 64) {
      float p = s2[t] * W3s[t];
      for (int off = 32; off > 0; off >>= 1) p += __shfl_down(p, off);
      if (t == 0) out[g] = p + b3[0];
    }
    __syncthreads();
  }
}

// ---------------------------------------------------------------------------
extern "C" void kernel_launch(void* const* d_in, const int* in_sizes, int n_in,
                              void* d_out, int out_size, void* d_ws, size_t ws_size,
                              hipStream_t stream) {
  const float* feats  = (const float*)d_in[0];
  const int*   src    = (const int*)d_in[1];
  const int*   dst    = (const int*)d_in[2];
  const int*   gids   = (const int*)d_in[3];
  const float* Wself  = (const float*)d_in[4];
  const float* Wneigh = (const float*)d_in[5];
  const float* bneigh = (const float*)d_in[6];
  const float* W1  = (const float*)d_in[7];
  const float* b1  = (const float*)d_in[8];
  const float* g1  = (const float*)d_in[9];
  const float* be1 = (const float*)d_in[10];
  const float* rm1 = (const float*)d_in[11];
  const float* rv1 = (const float*)d_in[12];
  const float* W2  = (const float*)d_in[13];
  const float* b2  = (const float*)d_in[14];
  const float* g2  = (const float*)d_in[15];
  const float* be2 = (const float*)d_in[16];
  const float* rm2 = (const float*)d_in[17];
  const float* rv2 = (const float*)d_in[18];
  const float* W3  = (const float*)d_in[19];
  const float* b3  = (const float*)d_in[20];

  // ws layout: Uh | Zh | Wh | gcur | hgbits | pairs  (gcur+hgbits = one memset)
  __half* Uh   = (__half*)d_ws;                      // N_NODES*64 halves
  __half* Zh   = Uh + (size_t)N_NODES * F;           // N_NODES*64 halves
  __half* Wh   = Zh + (size_t)N_NODES * F;           // 128*64 halves
  int* gcur    = (int*)(Wh + 128 * 64);              // NBUCK
  int* hgbits  = gcur + NBUCK;                       // N_GRAPHS*F
  int* pairs   = hgbits + (size_t)N_GRAPHS * F;      // NBUCK*CE slabs

  hipMemsetAsync(gcur, 0, (NBUCK + N_GRAPHS * F) * sizeof(int), stream);

  prepw<<<1, 256, 0, stream>>>(Wself, Wneigh, Wh);
  prepscat<<<NBLK + GEMM_BLOCKS, 256, 0, stream>>>(feats, Wh, Uh, Zh,
                                                   src, dst, gcur, pairs);
  gather_place<<<NBUCK, 1024, 0, stream>>>(Uh, Zh, pairs, gcur, bneigh,
                                           gids, hgbits);
  mlp<<<N_GRAPHS / GPB, 128, 0, stream>>>((const float*)hgbits,
                                          W1, b1, g1, be1, rm1, rv1,
                                          W2, b2, g2, be2, rm2, rv2, W3, b3,
                                          (float*)d_out);
}